// Round 17
// baseline (119.580 us; speedup 1.0000x reference)
//
#include <hip/hip_runtime.h>
#include <hip/hip_fp16.h>
#include <math.h>

#define IN_CH 128
#define OUT_CH 16
#define B 256
#define CH_H 2048         // edges per histogram chunk
#define CH_P 4096         // edges per placement chunk (F = CH_P/CH_H = 2)
#define LSH 6             // leaf = node >> 6  (64 nodes per leaf)
#define LNODES 64
#define NW 4              // waves per block (B/64)
#define MAXS 4096         // max records staged per leaf in k_sort2
#define MAXNL 1024
#define MAXGH 2048

__device__ __forceinline__ unsigned short f2h(float f) {
    __half h = __float2half(f);
    unsigned short u;
    __builtin_memcpy(&u, &h, 2);
    return u;
}
__device__ __forceinline__ float h2f(unsigned short u) {
    __half h;
    __builtin_memcpy(&h, &u, 2);
    return __half2float(h);
}

// exclusive prefix of vals[0..NL) into dst (LDS), B threads, 4 bins/thread
__device__ __forceinline__ void scan_nl(const unsigned* __restrict__ vals, unsigned* dst,
                                        unsigned* sums, int NL) {
    int tid = threadIdx.x;
    int b0 = tid * 4;
    unsigned v[4]; unsigned loc = 0;
#pragma unroll
    for (int q = 0; q < 4; ++q) { int i = b0 + q; v[q] = (i < NL) ? vals[i] : 0u; loc += v[q]; }
    sums[tid] = loc;
    __syncthreads();
    for (int off = 1; off < B; off <<= 1) {
        unsigned a = (tid >= off) ? sums[tid - off] : 0u;
        __syncthreads();
        sums[tid] += a;
        __syncthreads();
    }
    unsigned run = sums[tid] - loc;
#pragma unroll
    for (int q = 0; q < 4; ++q) { int i = b0 + q; if (i < NL) dst[i] = run; run += v[q]; }
    __syncthreads();
}

// --- fused: per-chunk leaf histogram (blocks < G_H) + projection p = x@W^T (rest) ---
__global__ void __launch_bounds__(B)
k_histproj(const int* __restrict__ col, unsigned* __restrict__ bh,
           const float* __restrict__ x, const float* __restrict__ W,
           float* __restrict__ p, int E, int N, int NL, int G_H) {
    __shared__ unsigned hc[MAXNL];
    __shared__ float sW[OUT_CH * 132];
    int tid = threadIdx.x;
    if ((int)blockIdx.x < G_H) {
        for (int i = tid; i < NL; i += B) hc[i] = 0u;
        __syncthreads();
        int base = blockIdx.x * CH_H;
        int end = base + CH_H < E ? base + CH_H : E;
        for (int e = base + tid; e < end; e += B)
            atomicAdd(&hc[col[e] >> LSH], 1u);
        __syncthreads();
        unsigned* out = bh + (size_t)blockIdx.x * NL;
        for (int i = tid; i < NL; i += B) out[i] = hc[i];
    } else {
        for (int i = tid; i < OUT_CH * IN_CH; i += B)
            sW[(i >> 7) * 132 + (i & 127)] = W[i];
        __syncthreads();
        int n = ((int)blockIdx.x - G_H) * 16 + (tid >> 4);
        int o = tid & 15;
        if (n >= N) return;
        const float* xr = x + (size_t)n * IN_CH;
        const float* wr = sW + o * 132;
        float acc = 0.0f;
#pragma unroll
        for (int k = 0; k < IN_CH; k += 4) {
            float4 xv = *reinterpret_cast<const float4*>(xr + k);
            float4 wv = *reinterpret_cast<const float4*>(wr + k);
            acc += xv.x * wv.x + xv.y * wv.y + xv.z * wv.z + xv.w * wv.w;
        }
        p[(size_t)n * OUT_CH + o] = acc;
    }
}

// --- per-leaf exclusive scan over chunks (loops over G with carry); totals out ---
__global__ void __launch_bounds__(B) k_colscan(unsigned* __restrict__ bh,
                                               unsigned* __restrict__ tot, int G, int NL) {
    int j = blockIdx.x;
    __shared__ unsigned s[B];
    int tid = threadIdx.x;
    unsigned carry = 0;
    for (int g0 = 0; g0 < G; g0 += B) {
        __syncthreads();
        int g = g0 + tid;
        unsigned v = (g < G) ? bh[(size_t)g * NL + j] : 0u;
        s[tid] = v;
        __syncthreads();
        for (int off = 1; off < B; off <<= 1) {
            unsigned add = (tid >= off) ? s[tid - off] : 0u;
            __syncthreads();
            s[tid] += add;
            __syncthreads();
        }
        if (g < G) bh[(size_t)g * NL + j] = carry + s[tid] - v;
        carry += s[B - 1];
    }
    if (tid == 0) tot[j] = carry;
}

// --- placement: lscan derived from bh (no count pass); LDS-staged, coalesced IO ---
__global__ void __launch_bounds__(B)
k_place(const int* __restrict__ row, const int* __restrict__ col, const float* __restrict__ ew,
        const unsigned* __restrict__ bh, const unsigned* __restrict__ tot,
        uint2* __restrict__ rec, int E, int NL, int G_H, int F) {
    __shared__ uint2 srec[CH_P];                    // 32 KB
    __shared__ unsigned short slf[CH_P];            // 8 KB
    __shared__ unsigned obase[MAXNL];               // gbase[lf] + bh[g0][lf]
    __shared__ unsigned lscan[MAXNL];
    __shared__ unsigned lctr[MAXNL];
    __shared__ unsigned sums[B];
    int tid = threadIdx.x;
    int c = blockIdx.x;
    int base = c * CH_P;
    int end = base + CH_P < E ? base + CH_P : E;
    int cnt = end - base;
    int g0 = c * F;

    scan_nl(tot, lscan, sums, NL);      // gbase in lscan (temp)
    {
        const unsigned* r0 = bh + (size_t)g0 * NL;
        bool has2 = (g0 + F) < G_H;
        const unsigned* r2 = bh + (size_t)(g0 + F) * NL;
        for (int i = tid; i < NL; i += B) {
            unsigned b0 = r0[i];
            unsigned bn = has2 ? r2[i] : tot[i];
            obase[i] = lscan[i] + b0;
            lctr[i] = bn - b0;          // K: this chunk's per-leaf count
        }
    }
    __syncthreads();
    scan_nl(lctr, lscan, sums, NL);     // local chunk bases
    for (int i = tid; i < NL; i += B) lctr[i] = lscan[i];
    __syncthreads();
    for (int j = tid; j < cnt; j += B) {            // build records at sorted LDS position
        int e = base + j;
        int cc = col[e];
        int lf = cc >> LSH;
        unsigned pos = atomicAdd(&lctr[lf], 1u);
        srec[pos] = make_uint2(((unsigned)row[e] << 6) | (unsigned)(cc & (LNODES - 1)),
                               __float_as_uint(ew[e]));
        slf[pos] = (unsigned short)lf;
    }
    __syncthreads();
    for (int j = tid; j < cnt; j += B) {            // stream LDS -> global (run-coalesced)
        int lf = slf[j];
        unsigned outp = obase[lf] + ((unsigned)j - lscan[lf]);
        rec[outp] = srec[j];
    }
}

// --- node-sort within leaf, SINGLE atomic pass: hist rank IS the scatter rank ---
__global__ void __launch_bounds__(B)
k_sort2(const uint2* __restrict__ rec, const unsigned* __restrict__ tot,
        unsigned* __restrict__ rec2, unsigned* __restrict__ nptr,
        float* __restrict__ dinv, int N, int NL) {
    __shared__ unsigned sums[B];
    __shared__ unsigned gbase[MAXNL];
    __shared__ uint2 srec[MAXS];                 // 32 KB record stage
    __shared__ unsigned short pos16[MAXS];       // 8 KB per-wave ranks
    __shared__ unsigned cnt4[NW * LNODES];
    __shared__ unsigned start4[NW * LNODES];
    __shared__ unsigned nstart[LNODES];
    int l = blockIdx.x, tid = threadIdx.x;
    int w = tid >> 6;
    scan_nl(tot, gbase, sums, NL);
    int seg = (int)gbase[l];
    int cnt = (int)tot[l];
    for (int i = tid; i < NW * LNODES; i += B) cnt4[i] = 0u;
    __syncthreads();
    bool staged = (cnt <= MAXS);
    if (staged) {
        for (int s = tid; s < cnt; s += B) {     // pass A: read rec once, rank + stage
            uint2 u = rec[seg + s];
            int cc = (int)(u.x & (LNODES - 1));
            unsigned r = atomicAdd(&cnt4[w * LNODES + cc], 1u);
            srec[s] = u;
            pos16[s] = (unsigned short)r;
        }
    } else {                                     // overflow guard: plain hist
        for (int s = tid; s < cnt; s += B)
            atomicAdd(&cnt4[w * LNODES + (rec[seg + s].x & (LNODES - 1))], 1u);
    }
    __syncthreads();
    if (tid < LNODES) {
        unsigned c0 = cnt4[tid], c1 = cnt4[LNODES + tid];
        unsigned c2 = cnt4[2 * LNODES + tid], c3 = cnt4[3 * LNODES + tid];
        unsigned totn = c0 + c1 + c2 + c3;
        unsigned sum = totn;
        for (int off = 1; off < LNODES; off <<= 1) {    // one-wave shfl scan
            unsigned o = __shfl_up(sum, off, 64);
            if (tid >= off) sum += o;
        }
        unsigned st = (unsigned)seg + sum - totn;       // exclusive node base
        nstart[tid] = st;
        start4[tid] = st;
        start4[LNODES + tid] = st + c0;
        start4[2 * LNODES + tid] = st + c0 + c1;
        start4[3 * LNODES + tid] = st + c0 + c1 + c2;
        int n = l * LNODES + tid;
        if (n < N) nptr[n] = st;
    }
    if (l == NL - 1 && tid == 0) nptr[N] = (unsigned)(seg + cnt);
    __syncthreads();
    if (staged) {
        for (int s = tid; s < cnt; s += B) {     // pass B: LDS -> rec2, no atomics
            uint2 u = srec[s];
            int cc = (int)(u.x & (LNODES - 1));
            unsigned pos = start4[w * LNODES + cc] + pos16[s];
            rec2[pos] = ((u.x >> 6) << 16) | (unsigned)f2h(__uint_as_float(u.y));
        }
    } else {                                     // overflow guard: atomic rank scatter
        for (int s = tid; s < cnt; s += B) {
            uint2 u = rec[seg + s];
            int cc = (int)(u.x & (LNODES - 1));
            unsigned pos = atomicAdd(&start4[w * LNODES + cc], 1u);
            rec2[pos] = ((u.x >> 6) << 16) | (unsigned)f2h(__uint_as_float(u.y));
        }
    }
    __syncthreads();   // rec2 runs complete; coalesced readback for degrees
    int o = tid & 15;
    for (int nl = tid >> 4; nl < LNODES; nl += 16) {
        int j0 = (int)nstart[nl];
        int j1 = (nl + 1 < LNODES) ? (int)nstart[nl + 1] : seg + cnt;
        float wsum = 0.f;
        for (int j = j0 + o; j < j1; j += 16) wsum += h2f((unsigned short)rec2[j]);
#pragma unroll
        for (int off = 1; off < 16; off <<= 1) wsum += __shfl_xor(wsum, off, 16);
        if (o == 0) {
            int n = l * LNODES + nl;
            if (n < N) dinv[n] = rsqrtf(1.0f + wsum);
        }
    }
}

// --- CSR hops. FIRST: g1 = d^2 (d*p[n] + sum w*dinv[r]*p[r]).  else: final log-softmax ---
template <bool FIRST>
__global__ void __launch_bounds__(B)
k_hop(const unsigned* __restrict__ rec2, const unsigned* __restrict__ nptr,
      const float* __restrict__ dinv, const float* __restrict__ gin,
      float* __restrict__ out, int N) {
    int t = blockIdx.x * B + threadIdx.x;
    int n = t >> 4, ch = t & 15;
    if (n >= N) return;
    int j0 = (int)nptr[n], j1 = (int)nptr[n + 1];
    float acc = 0.f;
    int j = j0;
    for (; j + 3 < j1; j += 4) {  // 4-wide for MLP
        unsigned u0 = rec2[j], u1 = rec2[j + 1], u2 = rec2[j + 2], u3 = rec2[j + 3];
        float w0 = h2f((unsigned short)u0), w1 = h2f((unsigned short)u1);
        float w2 = h2f((unsigned short)u2), w3 = h2f((unsigned short)u3);
        if (FIRST) {
            w0 *= dinv[u0 >> 16]; w1 *= dinv[u1 >> 16];
            w2 *= dinv[u2 >> 16]; w3 *= dinv[u3 >> 16];
        }
        acc += w0 * gin[(size_t)(u0 >> 16) * OUT_CH + ch]
             + w1 * gin[(size_t)(u1 >> 16) * OUT_CH + ch]
             + w2 * gin[(size_t)(u2 >> 16) * OUT_CH + ch]
             + w3 * gin[(size_t)(u3 >> 16) * OUT_CH + ch];
    }
    for (; j < j1; ++j) {
        unsigned u = rec2[j];
        float ww = h2f((unsigned short)u);
        if (FIRST) ww *= dinv[u >> 16];
        acc += ww * gin[(size_t)(u >> 16) * OUT_CH + ch];
    }
    float d = dinv[n];
    if (FIRST) {
        out[(size_t)n * OUT_CH + ch] = d * d * (d * gin[(size_t)n * OUT_CH + ch] + acc);
    } else {
        float v = d * (gin[(size_t)n * OUT_CH + ch] + acc);
        float m = v;
#pragma unroll
        for (int off = 1; off < 16; off <<= 1) m = fmaxf(m, __shfl_xor(m, off, 16));
        float se = expf(v - m);
#pragma unroll
        for (int off = 1; off < 16; off <<= 1) se += __shfl_xor(se, off, 16);
        out[(size_t)n * OUT_CH + ch] = v - m - logf(se);
    }
}

// ================= fallback path (proven r2 structure) =================

__global__ void fb_deginit(float* deg, int N) {
    int i = blockIdx.x * blockDim.x + threadIdx.x;
    if (i < N) deg[i] = 1.0f;
}
__global__ void fb_deg(const int* __restrict__ col, const float* __restrict__ ew,
                       float* deg, int E) {
    int e = blockIdx.x * blockDim.x + threadIdx.x;
    if (e < E) atomicAdd(&deg[col[e]], ew[e]);
}
__global__ void fb_dinv(const float* __restrict__ deg, float* dinv, int N) {
    int i = blockIdx.x * blockDim.x + threadIdx.x;
    if (i < N) dinv[i] = rsqrtf(deg[i]);
}
__global__ void fb_proj(const float* __restrict__ x, const float* __restrict__ W,
                        float* __restrict__ y, int N) {
    __shared__ float sW[OUT_CH * 132];
    for (int i = threadIdx.x; i < OUT_CH * IN_CH; i += blockDim.x) {
        sW[(i >> 7) * 132 + (i & 127)] = W[i];
    }
    __syncthreads();
    int t = threadIdx.x;
    int n = blockIdx.x * 16 + (t >> 4);
    int o = t & 15;
    if (n >= N) return;
    const float* xr = x + (size_t)n * IN_CH;
    const float* wr = sW + o * 132;
    float acc = 0.0f;
#pragma unroll
    for (int k = 0; k < IN_CH; k += 4) {
        float4 xv = *reinterpret_cast<const float4*>(xr + k);
        float4 wv = *reinterpret_cast<const float4*>(wr + k);
        acc += xv.x * wv.x + xv.y * wv.y + xv.z * wv.z + xv.w * wv.w;
    }
    y[(size_t)n * OUT_CH + o] = acc;
}
__global__ void fb_selfinit(const float* __restrict__ hin, const float* __restrict__ dinv,
                            float* __restrict__ hout, int N) {
    int idx = blockIdx.x * blockDim.x + threadIdx.x;
    if (idx < N * OUT_CH) {
        float d = dinv[idx >> 4];
        hout[idx] = d * d * hin[idx];
    }
}
__global__ void fb_scat(const int* __restrict__ row, const int* __restrict__ col,
                        const float* __restrict__ ew, const float* __restrict__ dinv,
                        const float* __restrict__ hin, float* __restrict__ hout, int E) {
    long long idx = (long long)blockIdx.x * blockDim.x + threadIdx.x;
    int e = (int)(idx >> 4);
    int c = (int)(idx & 15);
    if (e >= E) return;
    int r = row[e], cl = col[e];
    float nv = dinv[r] * ew[e] * dinv[cl];
    atomicAdd(&hout[(size_t)cl * OUT_CH + c], nv * hin[(size_t)r * OUT_CH + c]);
}
__global__ void fb_lsm(const float* __restrict__ h, float* __restrict__ out, int N) {
    int n = blockIdx.x * blockDim.x + threadIdx.x;
    if (n >= N) return;
    const float* hr = h + (size_t)n * OUT_CH;
    float v[OUT_CH];
#pragma unroll
    for (int i = 0; i < OUT_CH; i++) v[i] = hr[i];
    float m = v[0];
#pragma unroll
    for (int i = 1; i < OUT_CH; i++) m = fmaxf(m, v[i]);
    float s = 0.0f;
#pragma unroll
    for (int i = 0; i < OUT_CH; i++) s += expf(v[i] - m);
    float lse = m + logf(s);
    float* orow = out + (size_t)n * OUT_CH;
#pragma unroll
    for (int i = 0; i < OUT_CH; i++) orow[i] = v[i] - lse;
}

// ================= launch =================

extern "C" void kernel_launch(void* const* d_in, const int* in_sizes, int n_in,
                              void* d_out, int out_size, void* d_ws, size_t ws_size,
                              hipStream_t stream) {
    const float* x  = (const float*)d_in[0];
    const float* W  = (const float*)d_in[1];
    const float* ew = (const float*)d_in[2];
    const int*   ei = (const int*)d_in[3];  // harness pushes int64 as int32

    int N = in_sizes[0] / IN_CH;
    int E = in_sizes[2];
    const int* row = ei;       // source
    const int* col = ei + E;   // target

    auto al = [](size_t v) { return (v + 255) & ~(size_t)255; };
    size_t N16 = (size_t)N * OUT_CH;

    int NL  = (N + LNODES - 1) >> LSH;
    int G_H = (E + CH_H - 1) / CH_H;
    int G_P = (E + CH_P - 1) / CH_P;
    int F   = CH_P / CH_H;
    int NP16 = (N + 15) / 16;
    int gH  = (int)((N16 + B - 1) / B);

    size_t o_rec  = 0;
    size_t o_rec2 = o_rec  + al((size_t)E * 8);
    size_t o_bh   = o_rec2 + al((size_t)E * 4);
    size_t o_tot  = o_bh   + al((size_t)G_H * NL * 4);
    size_t o_nptr = o_tot  + al((size_t)NL * 4);
    size_t o_dinv = o_nptr + al((size_t)(N + 1) * 4);
    size_t o_p    = o_dinv + al((size_t)N * 4);
    size_t o_g1   = o_p    + al(N16 * 4);
    size_t need   = o_g1   + al(N16 * 4);

    bool shape_ok = (NL <= MAXNL && G_H <= MAXGH && N <= 65536 &&
                     (G_P * F) <= G_H + F);

    char* ws = (char*)d_ws;

    if (shape_ok && need <= ws_size) {
        uint2*    rec  = (uint2*)(ws + o_rec);
        unsigned* rec2 = (unsigned*)(ws + o_rec2);
        unsigned* bh   = (unsigned*)(ws + o_bh);
        unsigned* tot  = (unsigned*)(ws + o_tot);
        unsigned* nptr = (unsigned*)(ws + o_nptr);
        float*    dinv = (float*)(ws + o_dinv);
        float*    p    = (float*)(ws + o_p);
        float*    g1   = (float*)(ws + o_g1);

        k_histproj <<<G_H + NP16, B, 0, stream>>>(col, bh, x, W, p, E, N, NL, G_H);
        k_colscan  <<<NL,  B, 0, stream>>>(bh, tot, G_H, NL);
        k_place    <<<G_P, B, 0, stream>>>(row, col, ew, bh, tot, rec, E, NL, G_H, F);
        k_sort2    <<<NL,  B, 0, stream>>>(rec, tot, rec2, nptr, dinv, N, NL);
        k_hop<true ><<<gH, B, 0, stream>>>(rec2, nptr, dinv, p, g1, N);
        k_hop<false><<<gH, B, 0, stream>>>(rec2, nptr, dinv, g1, (float*)d_out, N);
    } else {
        // ---- fallback (r2-style, ~6.8 MB ws) ----
        size_t f_deg  = 0;
        size_t f_dinv = f_deg  + al((size_t)N * 4);
        size_t f_h0   = f_dinv + al((size_t)N * 4);
        size_t f_h1   = f_h0   + al(N16 * 4);
        float* deg  = (float*)(ws + f_deg);
        float* dinv = (float*)(ws + f_dinv);
        float* h0   = (float*)(ws + f_h0);
        float* h1   = (float*)(ws + f_h1);

        int gN   = (N + B - 1) / B;
        int gE   = (E + B - 1) / B;
        int gN16 = (N * OUT_CH + B - 1) / B;
        long long scat = (long long)E * OUT_CH;
        int gScat = (int)((scat + B - 1) / B);

        fb_deginit<<<gN, B, 0, stream>>>(deg, N);
        fb_deg<<<gE, B, 0, stream>>>(col, ew, deg, E);
        fb_dinv<<<gN, B, 0, stream>>>(deg, dinv, N);
        fb_proj<<<(N + 15) / 16, B, 0, stream>>>(x, W, h0, N);
        float* hin = h0; float* hout = h1;
        for (int k = 0; k < 2; k++) {
            fb_selfinit<<<gN16, B, 0, stream>>>(hin, dinv, hout, N);
            fb_scat<<<gScat, B, 0, stream>>>(row, col, ew, dinv, hin, hout, E);
            float* t = hin; hin = hout; hout = t;
        }
        fb_lsm<<<gN, B, 0, stream>>>(hin, (float*)d_out, N);
    }
}

// Round 18
// 112.936 us; speedup vs baseline: 1.0588x; 1.0588x over previous
//
#include <hip/hip_runtime.h>
#include <hip/hip_fp16.h>
#include <math.h>

#define IN_CH 128
#define OUT_CH 16
#define B 256
#define CH_H 2048         // edges per histogram chunk
#define CH_P 4096         // edges per placement chunk (F = CH_P/CH_H = 2)
#define LSH 6             // leaf = node >> 6  (64 nodes per leaf)
#define LNODES 64
#define NW 4              // waves per block (B/64)
#define MAXNL 1024
#define MAXGH 2048

__device__ __forceinline__ unsigned short f2h(float f) {
    __half h = __float2half(f);
    unsigned short u;
    __builtin_memcpy(&u, &h, 2);
    return u;
}
__device__ __forceinline__ float h2f(unsigned short u) {
    __half h;
    __builtin_memcpy(&h, &u, 2);
    return __half2float(h);
}

// exclusive prefix of vals[0..NL) into dst (LDS), B threads, 4 bins/thread
__device__ __forceinline__ void scan_nl(const unsigned* __restrict__ vals, unsigned* dst,
                                        unsigned* sums, int NL) {
    int tid = threadIdx.x;
    int b0 = tid * 4;
    unsigned v[4]; unsigned loc = 0;
#pragma unroll
    for (int q = 0; q < 4; ++q) { int i = b0 + q; v[q] = (i < NL) ? vals[i] : 0u; loc += v[q]; }
    sums[tid] = loc;
    __syncthreads();
    for (int off = 1; off < B; off <<= 1) {
        unsigned a = (tid >= off) ? sums[tid - off] : 0u;
        __syncthreads();
        sums[tid] += a;
        __syncthreads();
    }
    unsigned run = sums[tid] - loc;
#pragma unroll
    for (int q = 0; q < 4; ++q) { int i = b0 + q; if (i < NL) dst[i] = run; run += v[q]; }
    __syncthreads();
}

// --- fused: per-chunk leaf histogram (blocks < G_H) + projection p = x@W^T (rest) ---
__global__ void __launch_bounds__(B)
k_histproj(const int* __restrict__ col, unsigned* __restrict__ bh,
           const float* __restrict__ x, const float* __restrict__ W,
           float* __restrict__ p, int E, int N, int NL, int G_H) {
    __shared__ unsigned hc[MAXNL];
    __shared__ float sW[OUT_CH * 132];
    int tid = threadIdx.x;
    if ((int)blockIdx.x < G_H) {
        for (int i = tid; i < NL; i += B) hc[i] = 0u;
        __syncthreads();
        int base = blockIdx.x * CH_H;
        int end = base + CH_H < E ? base + CH_H : E;
        for (int e = base + tid; e < end; e += B)
            atomicAdd(&hc[col[e] >> LSH], 1u);
        __syncthreads();
        unsigned* out = bh + (size_t)blockIdx.x * NL;
        for (int i = tid; i < NL; i += B) out[i] = hc[i];
    } else {
        for (int i = tid; i < OUT_CH * IN_CH; i += B)
            sW[(i >> 7) * 132 + (i & 127)] = W[i];
        __syncthreads();
        int n = ((int)blockIdx.x - G_H) * 16 + (tid >> 4);
        int o = tid & 15;
        if (n >= N) return;
        const float* xr = x + (size_t)n * IN_CH;
        const float* wr = sW + o * 132;
        float acc = 0.0f;
#pragma unroll
        for (int k = 0; k < IN_CH; k += 4) {
            float4 xv = *reinterpret_cast<const float4*>(xr + k);
            float4 wv = *reinterpret_cast<const float4*>(wr + k);
            acc += xv.x * wv.x + xv.y * wv.y + xv.z * wv.z + xv.w * wv.w;
        }
        p[(size_t)n * OUT_CH + o] = acc;
    }
}

// --- per-leaf exclusive scan over chunks (loops over G with carry); totals out ---
__global__ void __launch_bounds__(B) k_colscan(unsigned* __restrict__ bh,
                                               unsigned* __restrict__ tot, int G, int NL) {
    int j = blockIdx.x;
    __shared__ unsigned s[B];
    int tid = threadIdx.x;
    unsigned carry = 0;
    for (int g0 = 0; g0 < G; g0 += B) {
        __syncthreads();
        int g = g0 + tid;
        unsigned v = (g < G) ? bh[(size_t)g * NL + j] : 0u;
        s[tid] = v;
        __syncthreads();
        for (int off = 1; off < B; off <<= 1) {
            unsigned add = (tid >= off) ? s[tid - off] : 0u;
            __syncthreads();
            s[tid] += add;
            __syncthreads();
        }
        if (g < G) bh[(size_t)g * NL + j] = carry + s[tid] - v;
        carry += s[B - 1];
    }
    if (tid == 0) tot[j] = carry;
}

// --- placement: lscan derived from bh (no count pass); LDS-staged, coalesced IO ---
__global__ void __launch_bounds__(B)
k_place(const int* __restrict__ row, const int* __restrict__ col, const float* __restrict__ ew,
        const unsigned* __restrict__ bh, const unsigned* __restrict__ tot,
        uint2* __restrict__ rec, int E, int NL, int G_H, int F) {
    __shared__ uint2 srec[CH_P];                    // 32 KB
    __shared__ unsigned short slf[CH_P];            // 8 KB
    __shared__ unsigned obase[MAXNL];               // gbase[lf] + bh[g0][lf]
    __shared__ unsigned lscan[MAXNL];
    __shared__ unsigned lctr[MAXNL];
    __shared__ unsigned sums[B];
    int tid = threadIdx.x;
    int c = blockIdx.x;
    int base = c * CH_P;
    int end = base + CH_P < E ? base + CH_P : E;
    int cnt = end - base;
    int g0 = c * F;

    scan_nl(tot, lscan, sums, NL);      // gbase in lscan (temp)
    {
        const unsigned* r0 = bh + (size_t)g0 * NL;
        bool has2 = (g0 + F) < G_H;
        const unsigned* r2 = bh + (size_t)(g0 + F) * NL;
        for (int i = tid; i < NL; i += B) {
            unsigned b0 = r0[i];
            unsigned bn = has2 ? r2[i] : tot[i];
            obase[i] = lscan[i] + b0;
            lctr[i] = bn - b0;          // K: this chunk's per-leaf count
        }
    }
    __syncthreads();
    scan_nl(lctr, lscan, sums, NL);     // local chunk bases
    for (int i = tid; i < NL; i += B) lctr[i] = lscan[i];
    __syncthreads();
    for (int j = tid; j < cnt; j += B) {            // build records at sorted LDS position
        int e = base + j;
        int cc = col[e];
        int lf = cc >> LSH;
        unsigned pos = atomicAdd(&lctr[lf], 1u);
        srec[pos] = make_uint2(((unsigned)row[e] << 6) | (unsigned)(cc & (LNODES - 1)),
                               __float_as_uint(ew[e]));
        slf[pos] = (unsigned short)lf;
    }
    __syncthreads();
    for (int j = tid; j < cnt; j += B) {            // stream LDS -> global (run-coalesced)
        int lf = slf[j];
        unsigned outp = obase[lf] + ((unsigned)j - lscan[lf]);
        rec[outp] = srec[j];
    }
}

// --- node-sort within leaf with PER-WAVE counters; rec2{row16|f16 w}, nptr, dinv ---
__global__ void __launch_bounds__(B)
k_sort2(const uint2* __restrict__ rec, const unsigned* __restrict__ tot,
        unsigned* __restrict__ rec2, unsigned* __restrict__ nptr,
        float* __restrict__ dinv, int N, int NL) {
    __shared__ unsigned sums[B];
    __shared__ unsigned gbase[MAXNL];
    __shared__ unsigned cnt4[NW * LNODES];
    __shared__ unsigned start4[NW * LNODES];
    __shared__ unsigned nstart[LNODES];
    int l = blockIdx.x, tid = threadIdx.x;
    int w = tid >> 6;
    scan_nl(tot, gbase, sums, NL);
    int seg = (int)gbase[l];
    int cnt = (int)tot[l];
    for (int i = tid; i < NW * LNODES; i += B) cnt4[i] = 0u;
    __syncthreads();
    for (int j = seg + tid; j < seg + cnt; j += B)      // per-wave hist (low conflict)
        atomicAdd(&cnt4[w * LNODES + (rec[j].x & (LNODES - 1))], 1u);
    __syncthreads();
    if (tid < LNODES) {
        unsigned c0 = cnt4[tid], c1 = cnt4[LNODES + tid];
        unsigned c2 = cnt4[2 * LNODES + tid], c3 = cnt4[3 * LNODES + tid];
        unsigned totn = c0 + c1 + c2 + c3;
        unsigned sum = totn;
        for (int off = 1; off < LNODES; off <<= 1) {    // one-wave shfl scan
            unsigned o = __shfl_up(sum, off, 64);
            if (tid >= off) sum += o;
        }
        unsigned st = (unsigned)seg + sum - totn;       // exclusive node base
        nstart[tid] = st;
        start4[tid] = st;
        start4[LNODES + tid] = st + c0;
        start4[2 * LNODES + tid] = st + c0 + c1;
        start4[3 * LNODES + tid] = st + c0 + c1 + c2;
        int n = l * LNODES + tid;
        if (n < N) nptr[n] = st;
    }
    if (l == NL - 1 && tid == 0) nptr[N] = (unsigned)(seg + cnt);
    __syncthreads();
    for (int j = seg + tid; j < seg + cnt; j += B) {    // per-wave rank scatter (exact)
        uint2 u = rec[j];
        int cc = (int)(u.x & (LNODES - 1));
        unsigned pos = atomicAdd(&start4[w * LNODES + cc], 1u);
        rec2[pos] = ((u.x >> 6) << 16) | (unsigned)f2h(__uint_as_float(u.y));
    }
    __syncthreads();   // block-local rec2 runs complete; readback for degrees
    int o = tid & 15;
    for (int nl = tid >> 4; nl < LNODES; nl += 16) {
        int j0 = (int)nstart[nl];
        int j1 = (nl + 1 < LNODES) ? (int)nstart[nl + 1] : seg + cnt;
        float wsum = 0.f;
        for (int j = j0 + o; j < j1; j += 16) wsum += h2f((unsigned short)rec2[j]);
#pragma unroll
        for (int off = 1; off < 16; off <<= 1) wsum += __shfl_xor(wsum, off, 16);
        if (o == 0) {
            int n = l * LNODES + nl;
            if (n < N) dinv[n] = rsqrtf(1.0f + wsum);
        }
    }
}

// --- CSR hops. FIRST: g1 = d^2 (d*p[n] + sum w*dinv[r]*p[r]).  else: final log-softmax ---
template <bool FIRST>
__global__ void __launch_bounds__(B)
k_hop(const unsigned* __restrict__ rec2, const unsigned* __restrict__ nptr,
      const float* __restrict__ dinv, const float* __restrict__ gin,
      float* __restrict__ out, int N) {
    int t = blockIdx.x * B + threadIdx.x;
    int n = t >> 4, ch = t & 15;
    if (n >= N) return;
    int j0 = (int)nptr[n], j1 = (int)nptr[n + 1];
    float acc = 0.f;
    int j = j0;
    for (; j + 3 < j1; j += 4) {  // 4-wide for MLP
        unsigned u0 = rec2[j], u1 = rec2[j + 1], u2 = rec2[j + 2], u3 = rec2[j + 3];
        float w0 = h2f((unsigned short)u0), w1 = h2f((unsigned short)u1);
        float w2 = h2f((unsigned short)u2), w3 = h2f((unsigned short)u3);
        if (FIRST) {
            w0 *= dinv[u0 >> 16]; w1 *= dinv[u1 >> 16];
            w2 *= dinv[u2 >> 16]; w3 *= dinv[u3 >> 16];
        }
        acc += w0 * gin[(size_t)(u0 >> 16) * OUT_CH + ch]
             + w1 * gin[(size_t)(u1 >> 16) * OUT_CH + ch]
             + w2 * gin[(size_t)(u2 >> 16) * OUT_CH + ch]
             + w3 * gin[(size_t)(u3 >> 16) * OUT_CH + ch];
    }
    for (; j < j1; ++j) {
        unsigned u = rec2[j];
        float ww = h2f((unsigned short)u);
        if (FIRST) ww *= dinv[u >> 16];
        acc += ww * gin[(size_t)(u >> 16) * OUT_CH + ch];
    }
    float d = dinv[n];
    if (FIRST) {
        out[(size_t)n * OUT_CH + ch] = d * d * (d * gin[(size_t)n * OUT_CH + ch] + acc);
    } else {
        float v = d * (gin[(size_t)n * OUT_CH + ch] + acc);
        float m = v;
#pragma unroll
        for (int off = 1; off < 16; off <<= 1) m = fmaxf(m, __shfl_xor(m, off, 16));
        float se = expf(v - m);
#pragma unroll
        for (int off = 1; off < 16; off <<= 1) se += __shfl_xor(se, off, 16);
        out[(size_t)n * OUT_CH + ch] = v - m - logf(se);
    }
}

// ================= fallback path (proven r2 structure) =================

__global__ void fb_deginit(float* deg, int N) {
    int i = blockIdx.x * blockDim.x + threadIdx.x;
    if (i < N) deg[i] = 1.0f;
}
__global__ void fb_deg(const int* __restrict__ col, const float* __restrict__ ew,
                       float* deg, int E) {
    int e = blockIdx.x * blockDim.x + threadIdx.x;
    if (e < E) atomicAdd(&deg[col[e]], ew[e]);
}
__global__ void fb_dinv(const float* __restrict__ deg, float* dinv, int N) {
    int i = blockIdx.x * blockDim.x + threadIdx.x;
    if (i < N) dinv[i] = rsqrtf(deg[i]);
}
__global__ void fb_proj(const float* __restrict__ x, const float* __restrict__ W,
                        float* __restrict__ y, int N) {
    __shared__ float sW[OUT_CH * 132];
    for (int i = threadIdx.x; i < OUT_CH * IN_CH; i += blockDim.x) {
        sW[(i >> 7) * 132 + (i & 127)] = W[i];
    }
    __syncthreads();
    int t = threadIdx.x;
    int n = blockIdx.x * 16 + (t >> 4);
    int o = t & 15;
    if (n >= N) return;
    const float* xr = x + (size_t)n * IN_CH;
    const float* wr = sW + o * 132;
    float acc = 0.0f;
#pragma unroll
    for (int k = 0; k < IN_CH; k += 4) {
        float4 xv = *reinterpret_cast<const float4*>(xr + k);
        float4 wv = *reinterpret_cast<const float4*>(wr + k);
        acc += xv.x * wv.x + xv.y * wv.y + xv.z * wv.z + xv.w * wv.w;
    }
    y[(size_t)n * OUT_CH + o] = acc;
}
__global__ void fb_selfinit(const float* __restrict__ hin, const float* __restrict__ dinv,
                            float* __restrict__ hout, int N) {
    int idx = blockIdx.x * blockDim.x + threadIdx.x;
    if (idx < N * OUT_CH) {
        float d = dinv[idx >> 4];
        hout[idx] = d * d * hin[idx];
    }
}
__global__ void fb_scat(const int* __restrict__ row, const int* __restrict__ col,
                        const float* __restrict__ ew, const float* __restrict__ dinv,
                        const float* __restrict__ hin, float* __restrict__ hout, int E) {
    long long idx = (long long)blockIdx.x * blockDim.x + threadIdx.x;
    int e = (int)(idx >> 4);
    int c = (int)(idx & 15);
    if (e >= E) return;
    int r = row[e], cl = col[e];
    float nv = dinv[r] * ew[e] * dinv[cl];
    atomicAdd(&hout[(size_t)cl * OUT_CH + c], nv * hin[(size_t)r * OUT_CH + c]);
}
__global__ void fb_lsm(const float* __restrict__ h, float* __restrict__ out, int N) {
    int n = blockIdx.x * blockDim.x + threadIdx.x;
    if (n >= N) return;
    const float* hr = h + (size_t)n * OUT_CH;
    float v[OUT_CH];
#pragma unroll
    for (int i = 0; i < OUT_CH; i++) v[i] = hr[i];
    float m = v[0];
#pragma unroll
    for (int i = 1; i < OUT_CH; i++) m = fmaxf(m, v[i]);
    float s = 0.0f;
#pragma unroll
    for (int i = 0; i < OUT_CH; i++) s += expf(v[i] - m);
    float lse = m + logf(s);
    float* orow = out + (size_t)n * OUT_CH;
#pragma unroll
    for (int i = 0; i < OUT_CH; i++) orow[i] = v[i] - lse;
}

// ================= launch =================

extern "C" void kernel_launch(void* const* d_in, const int* in_sizes, int n_in,
                              void* d_out, int out_size, void* d_ws, size_t ws_size,
                              hipStream_t stream) {
    const float* x  = (const float*)d_in[0];
    const float* W  = (const float*)d_in[1];
    const float* ew = (const float*)d_in[2];
    const int*   ei = (const int*)d_in[3];  // harness pushes int64 as int32

    int N = in_sizes[0] / IN_CH;
    int E = in_sizes[2];
    const int* row = ei;       // source
    const int* col = ei + E;   // target

    auto al = [](size_t v) { return (v + 255) & ~(size_t)255; };
    size_t N16 = (size_t)N * OUT_CH;

    int NL  = (N + LNODES - 1) >> LSH;
    int G_H = (E + CH_H - 1) / CH_H;
    int G_P = (E + CH_P - 1) / CH_P;
    int F   = CH_P / CH_H;
    int NP16 = (N + 15) / 16;
    int gH  = (int)((N16 + B - 1) / B);

    size_t o_rec  = 0;
    size_t o_rec2 = o_rec  + al((size_t)E * 8);
    size_t o_bh   = o_rec2 + al((size_t)E * 4);
    size_t o_tot  = o_bh   + al((size_t)G_H * NL * 4);
    size_t o_nptr = o_tot  + al((size_t)NL * 4);
    size_t o_dinv = o_nptr + al((size_t)(N + 1) * 4);
    size_t o_p    = o_dinv + al((size_t)N * 4);
    size_t o_g1   = o_p    + al(N16 * 4);
    size_t need   = o_g1   + al(N16 * 4);

    bool shape_ok = (NL <= MAXNL && G_H <= MAXGH && N <= 65536 &&
                     (G_P * F) <= G_H + F);

    char* ws = (char*)d_ws;

    if (shape_ok && need <= ws_size) {
        uint2*    rec  = (uint2*)(ws + o_rec);
        unsigned* rec2 = (unsigned*)(ws + o_rec2);
        unsigned* bh   = (unsigned*)(ws + o_bh);
        unsigned* tot  = (unsigned*)(ws + o_tot);
        unsigned* nptr = (unsigned*)(ws + o_nptr);
        float*    dinv = (float*)(ws + o_dinv);
        float*    p    = (float*)(ws + o_p);
        float*    g1   = (float*)(ws + o_g1);

        k_histproj <<<G_H + NP16, B, 0, stream>>>(col, bh, x, W, p, E, N, NL, G_H);
        k_colscan  <<<NL,  B, 0, stream>>>(bh, tot, G_H, NL);
        k_place    <<<G_P, B, 0, stream>>>(row, col, ew, bh, tot, rec, E, NL, G_H, F);
        k_sort2    <<<NL,  B, 0, stream>>>(rec, tot, rec2, nptr, dinv, N, NL);
        k_hop<true ><<<gH, B, 0, stream>>>(rec2, nptr, dinv, p, g1, N);
        k_hop<false><<<gH, B, 0, stream>>>(rec2, nptr, dinv, g1, (float*)d_out, N);
    } else {
        // ---- fallback (r2-style, ~6.8 MB ws) ----
        size_t f_deg  = 0;
        size_t f_dinv = f_deg  + al((size_t)N * 4);
        size_t f_h0   = f_dinv + al((size_t)N * 4);
        size_t f_h1   = f_h0   + al(N16 * 4);
        float* deg  = (float*)(ws + f_deg);
        float* dinv = (float*)(ws + f_dinv);
        float* h0   = (float*)(ws + f_h0);
        float* h1   = (float*)(ws + f_h1);

        int gN   = (N + B - 1) / B;
        int gE   = (E + B - 1) / B;
        int gN16 = (N * OUT_CH + B - 1) / B;
        long long scat = (long long)E * OUT_CH;
        int gScat = (int)((scat + B - 1) / B);

        fb_deginit<<<gN, B, 0, stream>>>(deg, N);
        fb_deg<<<gE, B, 0, stream>>>(col, ew, deg, E);
        fb_dinv<<<gN, B, 0, stream>>>(deg, dinv, N);
        fb_proj<<<(N + 15) / 16, B, 0, stream>>>(x, W, h0, N);
        float* hin = h0; float* hout = h1;
        for (int k = 0; k < 2; k++) {
            fb_selfinit<<<gN16, B, 0, stream>>>(hin, dinv, hout, N);
            fb_scat<<<gScat, B, 0, stream>>>(row, col, ew, dinv, hin, hout, E);
            float* t = hin; hin = hout; hout = t;
        }
        fb_lsm<<<gN, B, 0, stream>>>(hin, (float*)d_out, N);
    }
}